// Round 3
// baseline (40212.085 us; speedup 1.0000x reference)
//
#include <hip/hip_runtime.h>
#include <hip/hip_bf16.h>
#include <hip/hip_cooperative_groups.h>
#include <math.h>

namespace cg = cooperative_groups;

// Discriminator GRU: B=64, T=1024, S=1024.  R3: split-bf16 (hi/lo, 3-pass
// MFMA) for both phase-1 GEMM and recurrence -> fp32-grade accuracy.
//  K0: zero h buffers
//  K1: split W_ih and W_hh into bf16 hi/lo (ws)
//  K2: xg[t*64+b][3072] (fp32) = batch @ W_ih^T + b_ih (+b_hh r,z)  [3-pass MFMA]
//  K3: persistent cooperative GRU, 64 blocks, W-hi LDS-resident,
//      W-lo + h(hi/lo) as direct-from-L2 MFMA fragments, 1 grid.sync/step
//  K4: out = sigmoid(h_T . W_out + b_out)

#define BB 64
#define TT 1024
#define SS 1024
#define GG 3072
#define MM (BB * TT)

typedef __attribute__((ext_vector_type(8))) __bf16 bf16x8;
typedef __attribute__((ext_vector_type(4))) float f32x4;

__device__ __forceinline__ ushort f2bf(float x) {
  __hip_bfloat16 h = __float2bfloat16(x);
  return *(ushort*)&h;
}
__device__ __forceinline__ float bf2f(ushort u) {
  union { unsigned v; float f; } c;
  c.v = ((unsigned)u) << 16;
  return c.f;
}

// ---------------------------------------------------------------------------
// K0: zero the h buffer block (1 MB = 65536 uint4)
// ---------------------------------------------------------------------------
__global__ __launch_bounds__(256) void zero_kernel(uint4* __restrict__ p) {
  p[(size_t)blockIdx.x * 256 + threadIdx.x] = make_uint4(0, 0, 0, 0);
}

// ---------------------------------------------------------------------------
// K1: split fp32 weights into bf16 hi/lo. Rows [0,3072): W_ih; [3072,6144): W_hh.
// ---------------------------------------------------------------------------
__global__ __launch_bounds__(256) void splitw_kernel(
    const float* __restrict__ Wih, const float* __restrict__ Whh,
    ushort* __restrict__ WihHi, ushort* __restrict__ WihLo,
    ushort* __restrict__ WhhHi, ushort* __restrict__ WhhLo) {
  const int row = blockIdx.x;
  const float* src;
  ushort *dhi, *dlo;
  if (row < GG) {
    src = &Wih[(size_t)row * SS];
    dhi = &WihHi[(size_t)row * SS];
    dlo = &WihLo[(size_t)row * SS];
  } else {
    const int r = row - GG;
    src = &Whh[(size_t)r * SS];
    dhi = &WhhHi[(size_t)r * SS];
    dlo = &WhhLo[(size_t)r * SS];
  }
  const int k = threadIdx.x * 4;
  const float4 v = *(const float4*)&src[k];
  ushort4 hi, lo;
  hi.x = f2bf(v.x); lo.x = f2bf(v.x - bf2f(hi.x));
  hi.y = f2bf(v.y); lo.y = f2bf(v.y - bf2f(hi.y));
  hi.z = f2bf(v.z); lo.z = f2bf(v.z - bf2f(hi.z));
  hi.w = f2bf(v.w); lo.w = f2bf(v.w - bf2f(hi.w));
  *(ushort4*)&dhi[k] = hi;
  *(ushort4*)&dlo[k] = lo;
}

// ---------------------------------------------------------------------------
// K2: phase-1 GEMM, split-bf16 3-pass. C fp32 [m'=t*64+b][3072].
// 128x128 tile, BK=32, 4 waves 2x2, 4x4 MFMA tiles/wave. A converted from
// fp32 batch on the fly; W from pre-split hi/lo.
// ---------------------------------------------------------------------------
__global__ __launch_bounds__(256) void gemm_kernel(
    const float* __restrict__ batch, const ushort* __restrict__ WHi,
    const ushort* __restrict__ WLo, const float* __restrict__ b_ih,
    const float* __restrict__ b_hh, float* __restrict__ C) {
  __shared__ ushort AsHi[128][40];
  __shared__ ushort AsLo[128][40];
  __shared__ ushort BsHi[128][40];
  __shared__ ushort BsLo[128][40];

  const int tid = threadIdx.x;
  const int lane = tid & 63;
  const int wave = tid >> 6;
  const int wm = wave >> 1, wn = wave & 1;
  const int m0 = blockIdx.y * 128;
  const int n0 = blockIdx.x * 128;

  const int srow = tid >> 1;   // 0..127
  const int half = tid & 1;    // 16-elem half of BK=32

  // A global row for staging: m' = m0+srow -> batch[b][t][.]
  const int mb = (m0 + srow) & 63;
  const int mt_ = (m0 + srow) >> 6;
  const float* arow = &batch[((size_t)mb * TT + mt_) * SS];

  f32x4 acc[4][4];
#pragma unroll
  for (int i = 0; i < 4; ++i)
#pragma unroll
    for (int j = 0; j < 4; ++j) acc[i][j] = (f32x4){0.f, 0.f, 0.f, 0.f};

  for (int kt = 0; kt < SS / 32; ++kt) {
    const int kbase = kt * 32 + half * 16;
    // A: 16 fp32 -> hi/lo
    float4 va[4];
#pragma unroll
    for (int j = 0; j < 4; ++j) va[j] = *(const float4*)&arow[kbase + j * 4];
    ushort hi[16], lo[16];
#pragma unroll
    for (int e = 0; e < 16; ++e) {
      const float x = ((const float*)va)[e];
      const ushort h = f2bf(x);
      hi[e] = h;
      lo[e] = f2bf(x - bf2f(h));
    }
    *(uint4*)&AsHi[srow][half * 16] = *(uint4*)&hi[0];
    *(uint4*)&AsHi[srow][half * 16 + 8] = *(uint4*)&hi[8];
    *(uint4*)&AsLo[srow][half * 16] = *(uint4*)&lo[0];
    *(uint4*)&AsLo[srow][half * 16 + 8] = *(uint4*)&lo[8];
    // W: pre-split bf16
    const size_t wof = (size_t)(n0 + srow) * SS + kbase;
    *(uint4*)&BsHi[srow][half * 16] = *(const uint4*)&WHi[wof];
    *(uint4*)&BsHi[srow][half * 16 + 8] = *(const uint4*)&WHi[wof + 8];
    *(uint4*)&BsLo[srow][half * 16] = *(const uint4*)&WLo[wof];
    *(uint4*)&BsLo[srow][half * 16 + 8] = *(const uint4*)&WLo[wof + 8];
    __syncthreads();

    const int fk = (lane >> 4) * 8;
    const int fr = lane & 15;
    bf16x8 afh[4], afl[4], bfh[4], bfl[4];
#pragma unroll
    for (int mt = 0; mt < 4; ++mt) {
      afh[mt] = *(const bf16x8*)&AsHi[wm * 64 + mt * 16 + fr][fk];
      afl[mt] = *(const bf16x8*)&AsLo[wm * 64 + mt * 16 + fr][fk];
    }
#pragma unroll
    for (int nt = 0; nt < 4; ++nt) {
      bfh[nt] = *(const bf16x8*)&BsHi[wn * 64 + nt * 16 + fr][fk];
      bfl[nt] = *(const bf16x8*)&BsLo[wn * 64 + nt * 16 + fr][fk];
    }
#pragma unroll
    for (int mt = 0; mt < 4; ++mt)
#pragma unroll
      for (int nt = 0; nt < 4; ++nt) {
        acc[mt][nt] = __builtin_amdgcn_mfma_f32_16x16x32_bf16(
            afh[mt], bfh[nt], acc[mt][nt], 0, 0, 0);
        acc[mt][nt] = __builtin_amdgcn_mfma_f32_16x16x32_bf16(
            afl[mt], bfh[nt], acc[mt][nt], 0, 0, 0);
        acc[mt][nt] = __builtin_amdgcn_mfma_f32_16x16x32_bf16(
            afh[mt], bfl[nt], acc[mt][nt], 0, 0, 0);
      }
    __syncthreads();
  }

  // epilogue: bias + fp32 store. C/D: col=lane&15 (n), row=(lane>>4)*4+i (m).
#pragma unroll
  for (int nt = 0; nt < 4; ++nt) {
    const int n = n0 + wn * 64 + nt * 16 + (lane & 15);
    const float bias = b_ih[n] + (n < 2 * SS ? b_hh[n] : 0.f);
#pragma unroll
    for (int mt = 0; mt < 4; ++mt)
#pragma unroll
      for (int i = 0; i < 4; ++i) {
        const int m = m0 + wm * 64 + mt * 16 + (lane >> 4) * 4 + i;
        C[(size_t)m * GG + n] = acc[mt][nt][i] + bias;
      }
  }
}

// ---------------------------------------------------------------------------
// K3: persistent GRU. 64 blocks x 256 threads (4 waves).
// Block: units u0..u0+15, all 3 gates (48 W rows). Wave wv: batches 16wv..+15.
// W-hi resident in LDS (48x1032 ushort, pad 8 -> 2-way bank, free).
// Per step per wave: 32 k-iters x 3 ntiles x 3 passes = 288 MFMA.
// A-frags (h hi/lo) and B-lo frags loaded straight from global (L2-resident).
// ---------------------------------------------------------------------------
__global__ __launch_bounds__(256, 1) void gru_persistent(
    const ushort* __restrict__ WhhHi, const ushort* __restrict__ WhhLo,
    const float* __restrict__ xg, const float* __restrict__ bhh,
    float* __restrict__ hF0, float* __restrict__ hF1,
    ushort* __restrict__ hHi0, ushort* __restrict__ hHi1,
    ushort* __restrict__ hLo0, ushort* __restrict__ hLo1) {
  __shared__ ushort WhiL[48][1032];  // 99 KB

  const int tid = threadIdx.x;
  const int lane = tid & 63;
  const int wv = tid >> 6;          // m-tile (batch group)
  const int u0 = blockIdx.x * 16;
  const int fr = lane & 15;         // A: batch ofs / B: row ofs / C: unit col
  const int kg = (lane >> 4) * 8;   // k-group offset (elems)

  // resident W-hi load: 48 rows x 1024 = 6144 x 16B
#pragma unroll
  for (int i = 0; i < 24; ++i) {
    const int idx = tid + i * 256;
    const int r = idx >> 7;
    const int c8 = (idx & 127) * 8;
    const int g = r >> 4, uu = r & 15;
    *(uint4*)&WhiL[r][c8] =
        *(const uint4*)&WhhHi[((size_t)g * SS + u0 + uu) * SS + c8];
  }
  // B-lo global row bases (per lane)
  const ushort* wlo0 = &WhhLo[((size_t)0 * SS + u0 + fr) * SS + kg];
  const ushort* wlo1 = &WhhLo[((size_t)1 * SS + u0 + fr) * SS + kg];
  const ushort* wlo2 = &WhhLo[((size_t)2 * SS + u0 + fr) * SS + kg];

  cg::grid_group grid = cg::this_grid();
  __syncthreads();

  for (int t = 0; t < TT; ++t) {
    const int sel = t & 1;
    const float* hPf = sel ? hF1 : hF0;
    float* hNf = sel ? hF0 : hF1;
    const ushort* hPhi = sel ? hHi1 : hHi0;
    ushort* hNhi = sel ? hHi0 : hHi1;
    const ushort* hPlo = sel ? hLo1 : hLo0;
    ushort* hNlo = sel ? hLo0 : hLo1;

    // ---- prefetch epilogue operands (consumed after k-loop) ----
    float xr[4], xz[4], xn[4], hold[4];
#pragma unroll
    for (int i = 0; i < 4; ++i) {
      const int b = wv * 16 + (lane >> 4) * 4 + i;
      const int u = u0 + fr;
      const size_t xbase = ((size_t)t * BB + b) * GG;
      xr[i] = xg[xbase + u];
      xz[i] = xg[xbase + SS + u];
      xn[i] = xg[xbase + 2 * SS + u];
      hold[i] = hPf[(size_t)b * SS + u];
    }
    const float bhn = bhh[2 * SS + u0 + fr];

    // ---- k-loop: depth-1 software pipeline ----
    const ushort* ahp = &hPhi[((size_t)(wv * 16 + fr)) * SS + kg];
    const ushort* alp = &hPlo[((size_t)(wv * 16 + fr)) * SS + kg];

    f32x4 acc0 = (f32x4){0.f, 0.f, 0.f, 0.f};
    f32x4 acc1 = acc0, acc2 = acc0;

    bf16x8 ah[2], al[2], b0h[2], b1h[2], b2h[2], b0l[2], b1l[2], b2l[2];
    // kt=0 loads
    ah[0] = *(const bf16x8*)&ahp[0];
    al[0] = *(const bf16x8*)&alp[0];
    b0h[0] = *(const bf16x8*)&WhiL[fr][kg];
    b1h[0] = *(const bf16x8*)&WhiL[16 + fr][kg];
    b2h[0] = *(const bf16x8*)&WhiL[32 + fr][kg];
    b0l[0] = *(const bf16x8*)&wlo0[0];
    b1l[0] = *(const bf16x8*)&wlo1[0];
    b2l[0] = *(const bf16x8*)&wlo2[0];

#pragma unroll 2
    for (int kt = 0; kt < 32; ++kt) {
      const int c = kt & 1, nx = c ^ 1;
      if (kt < 31) {
        const int ko = (kt + 1) * 32;
        ah[nx] = *(const bf16x8*)&ahp[ko];
        al[nx] = *(const bf16x8*)&alp[ko];
        b0h[nx] = *(const bf16x8*)&WhiL[fr][ko + kg];
        b1h[nx] = *(const bf16x8*)&WhiL[16 + fr][ko + kg];
        b2h[nx] = *(const bf16x8*)&WhiL[32 + fr][ko + kg];
        b0l[nx] = *(const bf16x8*)&wlo0[ko];
        b1l[nx] = *(const bf16x8*)&wlo1[ko];
        b2l[nx] = *(const bf16x8*)&wlo2[ko];
      }
      acc0 = __builtin_amdgcn_mfma_f32_16x16x32_bf16(ah[c], b0h[c], acc0, 0, 0, 0);
      acc1 = __builtin_amdgcn_mfma_f32_16x16x32_bf16(ah[c], b1h[c], acc1, 0, 0, 0);
      acc2 = __builtin_amdgcn_mfma_f32_16x16x32_bf16(ah[c], b2h[c], acc2, 0, 0, 0);
      acc0 = __builtin_amdgcn_mfma_f32_16x16x32_bf16(al[c], b0h[c], acc0, 0, 0, 0);
      acc1 = __builtin_amdgcn_mfma_f32_16x16x32_bf16(al[c], b1h[c], acc1, 0, 0, 0);
      acc2 = __builtin_amdgcn_mfma_f32_16x16x32_bf16(al[c], b2h[c], acc2, 0, 0, 0);
      acc0 = __builtin_amdgcn_mfma_f32_16x16x32_bf16(ah[c], b0l[c], acc0, 0, 0, 0);
      acc1 = __builtin_amdgcn_mfma_f32_16x16x32_bf16(ah[c], b1l[c], acc1, 0, 0, 0);
      acc2 = __builtin_amdgcn_mfma_f32_16x16x32_bf16(ah[c], b2l[c], acc2, 0, 0, 0);
    }

    // ---- gate combine (lane-local: r,z,n of unit u in acc0/1/2) ----
#pragma unroll
    for (int i = 0; i < 4; ++i) {
      const int b = wv * 16 + (lane >> 4) * 4 + i;
      const int u = u0 + fr;
      const float r = 1.f / (1.f + __expf(-(xr[i] + acc0[i])));
      const float z = 1.f / (1.f + __expf(-(xz[i] + acc1[i])));
      const float nn = tanhf(xn[i] + r * (acc2[i] + bhn));
      const float hnew = (1.f - z) * nn + z * hold[i];
      hNf[(size_t)b * SS + u] = hnew;
      const ushort hh = f2bf(hnew);
      hNhi[(size_t)b * SS + u] = hh;
      hNlo[(size_t)b * SS + u] = f2bf(hnew - bf2f(hh));
    }

    __threadfence();
    grid.sync();
  }
}

// ---------------------------------------------------------------------------
// K4: out[b] = sigmoid(h[b] . W_out + b_out)
// ---------------------------------------------------------------------------
__global__ __launch_bounds__(256) void out_kernel(
    const float* __restrict__ h, const float* __restrict__ Wout,
    const float* __restrict__ bout, float* __restrict__ out) {
  const int b = blockIdx.x;
  const int tid = threadIdx.x;
  float s = 0.f;
#pragma unroll
  for (int i = 0; i < 4; ++i) {
    const int u = tid + i * 256;
    s = fmaf(h[(size_t)b * SS + u], Wout[u], s);
  }
#pragma unroll
  for (int off = 32; off; off >>= 1) s += __shfl_down(s, off);
  __shared__ float red[4];
  if ((tid & 63) == 0) red[tid >> 6] = s;
  __syncthreads();
  if (tid == 0) {
    const float tot = red[0] + red[1] + red[2] + red[3] + bout[0];
    out[b] = 1.f / (1.f + __expf(-tot));
  }
}

// ---------------------------------------------------------------------------
extern "C" void kernel_launch(void* const* d_in, const int* in_sizes, int n_in,
                              void* d_out, int out_size, void* d_ws,
                              size_t ws_size, hipStream_t stream) {
  const float* batch = (const float*)d_in[0];
  const float* W_ih = (const float*)d_in[1];
  const float* W_hh = (const float*)d_in[2];
  const float* b_ih = (const float*)d_in[3];
  const float* b_hh = (const float*)d_in[4];
  const float* W_out = (const float*)d_in[5];
  const float* b_out = (const float*)d_in[6];
  float* out = (float*)d_out;

  // ws carve: 768 MB xg + 4x6 MB W splits + 1 MB h = 793 MB
  char* w = (char*)d_ws;
  float* xg = (float*)w;                      w += (size_t)MM * GG * 4;
  ushort* WihHi = (ushort*)w;                 w += (size_t)GG * SS * 2;
  ushort* WihLo = (ushort*)w;                 w += (size_t)GG * SS * 2;
  ushort* WhhHi = (ushort*)w;                 w += (size_t)GG * SS * 2;
  ushort* WhhLo = (ushort*)w;                 w += (size_t)GG * SS * 2;
  char* hbase = w;
  float* hF0 = (float*)hbase;
  float* hF1 = hF0 + (size_t)BB * SS;
  ushort* hHi0 = (ushort*)(hF1 + (size_t)BB * SS);
  ushort* hHi1 = hHi0 + (size_t)BB * SS;
  ushort* hLo0 = hHi1 + (size_t)BB * SS;
  ushort* hLo1 = hLo0 + (size_t)BB * SS;

  // zero all h buffers (1 MB)
  zero_kernel<<<256, 256, 0, stream>>>((uint4*)hbase);
  // split weights
  splitw_kernel<<<2 * GG, 256, 0, stream>>>(W_ih, W_hh, WihHi, WihLo, WhhHi,
                                            WhhLo);
  // phase-1 GEMM
  gemm_kernel<<<dim3(GG / 128, MM / 128), 256, 0, stream>>>(batch, WihHi,
                                                            WihLo, b_ih, b_hh,
                                                            xg);
  // persistent recurrence
  void* args[] = {(void*)&WhhHi, (void*)&WhhLo, (void*)&xg, (void*)&b_hh,
                  (void*)&hF0,   (void*)&hF1,   (void*)&hHi0, (void*)&hHi1,
                  (void*)&hLo0,  (void*)&hLo1};
  hipLaunchCooperativeKernel((const void*)gru_persistent, dim3(64), dim3(256),
                             args, 0, stream);
  // t=1023 writes sel^1 = buf0 -> final h in hF0
  out_kernel<<<BB, 256, 0, stream>>>(hF0, W_out, b_out, out);
}